// Round 3
// baseline (68.286 us; speedup 1.0000x reference)
//
#include <hip/hip_runtime.h>
#include <hip/hip_bf16.h>

typedef __bf16 bf16x8 __attribute__((ext_vector_type(8)));
typedef __bf16 bf16x4 __attribute__((ext_vector_type(4)));
typedef float  f32x4  __attribute__((ext_vector_type(4)));
typedef float  f32x2  __attribute__((ext_vector_type(2)));

// Fused SO(2)-equivariant linear layer, transposed-GEMM formulation:
//   hT = W1^T @ s^T (relu, bias in acc-init) -> LDS as h[edge][hid] bf16
//   wT = W2^T @ hT  (bias in acc-init)       -> stays in registers
//   out[e,o] = complex contraction of x[e] with w[e,o,:], reduced via shfl_xor(16)
// One wave = 64 edges. mfma_f32_16x16x32_bf16, fp32 accumulate.
__global__ __launch_bounds__(256) void so2_fused_kernel(
    const float* __restrict__ x, const float* __restrict__ s,
    const float* __restrict__ W1, const float* __restrict__ b1v,
    const float* __restrict__ W2, const float* __restrict__ b2v,
    float* __restrict__ out, int E)
{
  __shared__ unsigned short lds_w1t[64 * 64];  // W1^T [j][k] bf16, XOR-swizzled
  __shared__ unsigned short lds_w2t[32 * 64];  // W2^T [d][k] bf16, XOR-swizzled
  __shared__ char lds_h[4][8192];              // per-wave h[edge=64][hid=64] bf16, swizzled

  const int tid  = threadIdx.x;
  const int wid  = tid >> 6;
  const int lane = tid & 63;
  const int lrow = lane & 15;
  const int lg   = lane >> 4;

  const int web = blockIdx.x * 256 + wid * 64;
  const bool wave_active = (web < E);
  const int base_e = wave_active ? web : 0;

  // ---- issue ALL independent global loads first: s (B-frag shape), x, biases ----
  f32x4 sv[4][4];
  #pragma unroll
  for (int et = 0; et < 4; ++et) {
    int er = base_e + et * 16 + lrow; er = er < E ? er : E - 1;
    const float* sp = s + (size_t)er * 64 + lg * 8;
    sv[et][0] = *(const f32x4*)(sp);
    sv[et][1] = *(const f32x4*)(sp + 4);
    sv[et][2] = *(const f32x4*)(sp + 32);
    sv[et][3] = *(const f32x4*)(sp + 36);
  }
  f32x4 xv[4];
  #pragma unroll
  for (int et = 0; et < 4; ++et) {
    int er = base_e + et * 16 + lrow; er = er < E ? er : E - 1;
    xv[et] = *(const f32x4*)(x + (size_t)er * 8 + (lg & 1) * 4);
  }
  f32x4 bias1[4], bias2[2];
  #pragma unroll
  for (int jt = 0; jt < 4; ++jt) bias1[jt] = *(const f32x4*)(b1v + jt * 16 + lg * 4);
  #pragma unroll
  for (int dt = 0; dt < 2; ++dt) bias2[dt] = *(const f32x4*)(b2v + dt * 16 + lg * 4);

  // ---- stage weights to LDS as bf16, transposed, XOR-swizzled (dwordx4 reads) ----
  #pragma unroll
  for (int it = 0; it < 4; ++it) {
    int i = (it * 256 + tid) * 4;            // 4 consecutive floats, same k row
    f32x4 v = *(const f32x4*)(W1 + i);
    int k = i >> 6, j = i & 63;
    #pragma unroll
    for (int q = 0; q < 4; ++q) {
      int byte = ((j + q) << 7) + (k << 1);
      byte ^= ((j + q) & 7) << 4;
      *(unsigned short*)((char*)lds_w1t + byte) =
          __builtin_bit_cast(unsigned short, (__bf16)v[q]);
    }
  }
  #pragma unroll
  for (int it = 0; it < 2; ++it) {
    int i = (it * 256 + tid) * 4;            // i = k*32 + d
    f32x4 v = *(const f32x4*)(W2 + i);
    int k = i >> 5, d = i & 31;
    #pragma unroll
    for (int q = 0; q < 4; ++q) {
      int byte = ((d + q) << 7) + (k << 1);
      byte ^= ((d + q) & 7) << 4;
      *(unsigned short*)((char*)lds_w2t + byte) =
          __builtin_bit_cast(unsigned short, (__bf16)v[q]);
    }
  }

  // ---- convert s to bf16 B-fragments (col=edge=lrow, k = c*32 + lg*8 + i) ----
  bf16x8 sf[4][2];
  #pragma unroll
  for (int et = 0; et < 4; ++et) {
    #pragma unroll
    for (int c = 0; c < 2; ++c) {
      #pragma unroll
      for (int i = 0; i < 4; ++i) {
        sf[et][c][i]     = (__bf16)sv[et][c * 2][i];
        sf[et][c][i + 4] = (__bf16)sv[et][c * 2 + 1][i];
      }
    }
  }

  __syncthreads();
  if (!wave_active) return;

  char* hbuf = lds_h[wid];

  // ---- GEMM1: hT = relu(W1^T @ s^T + b1); D: col=edge=lrow, row=hid=lg*4+r ----
  #pragma unroll
  for (int jt = 0; jt < 4; ++jt) {
    bf16x8 wf[2];
    #pragma unroll
    for (int c = 0; c < 2; ++c) {
      int j = jt * 16 + lrow;
      int byte = (j << 7) + ((c * 32 + lg * 8) << 1);
      byte ^= (j & 7) << 4;
      wf[c] = *(const bf16x8*)((const char*)lds_w1t + byte);
    }
    #pragma unroll
    for (int et = 0; et < 4; ++et) {
      f32x4 acc = bias1[jt];
      acc = __builtin_amdgcn_mfma_f32_16x16x32_bf16(wf[0], sf[et][0], acc, 0, 0, 0);
      acc = __builtin_amdgcn_mfma_f32_16x16x32_bf16(wf[1], sf[et][1], acc, 0, 0, 0);
      bf16x4 hv;
      #pragma unroll
      for (int r = 0; r < 4; ++r) hv[r] = (__bf16)fmaxf(acc[r], 0.f);
      // h[edge = et*16+lrow][hid = jt*16 + lg*4 .. +3], 8B write, swizzled
      int byte = ((et * 16 + lrow) << 7) + ((jt * 16 + lg * 4) << 1);
      byte ^= (lrow & 7) << 4;
      *(bf16x4*)(hbuf + byte) = hv;
    }
  }

  // ---- fence: h ds_writes must complete & must not be reordered vs h ds_reads.
  // (bf16x4 stores vs bf16x8 loads are distinct TBAA types; without this the
  //  compiler may hoist the reads. HW DS is in-order per wave; this also waits.)
  asm volatile("s_waitcnt lgkmcnt(0)" ::: "memory");
  __builtin_amdgcn_sched_barrier(0);

  // ---- GEMM2: wT = W2^T @ hT + b2; D: col=edge=lrow, d = dt*16 + lg*4 + r ----
  bf16x8 w2f[2][2];
  #pragma unroll
  for (int dt = 0; dt < 2; ++dt) {
    #pragma unroll
    for (int c = 0; c < 2; ++c) {
      int d = dt * 16 + lrow;
      int byte = (d << 7) + ((c * 32 + lg * 8) << 1);
      byte ^= (d & 7) << 4;
      w2f[dt][c] = *(const bf16x8*)((const char*)lds_w2t + byte);
    }
  }
  f32x4 wacc[4][2];
  #pragma unroll
  for (int et = 0; et < 4; ++et) {
    bf16x8 hf[2];
    #pragma unroll
    for (int c = 0; c < 2; ++c) {
      int byte = ((et * 16 + lrow) << 7) + ((c * 32 + lg * 8) << 1);
      byte ^= (lrow & 7) << 4;
      hf[c] = *(const bf16x8*)(hbuf + byte);
    }
    #pragma unroll
    for (int dt = 0; dt < 2; ++dt) {
      f32x4 acc = bias2[dt];
      acc = __builtin_amdgcn_mfma_f32_16x16x32_bf16(w2f[dt][0], hf[0], acc, 0, 0, 0);
      acc = __builtin_amdgcn_mfma_f32_16x16x32_bf16(w2f[dt][1], hf[1], acc, 0, 0, 0);
      wacc[et][dt] = acc;
    }
  }

  // ---- epilogue: in-register complex contraction ----
  // lane(lg,lrow) holds w[e=et*16+lrow][d=dt*16+lg*4+r]; d = o*8+2p+c with
  // o = 2*dt + (lg>>1), p = 2*(lg&1) + (r>>1), c = r&1.
  // xv[et] = {xr_P, xi_P, xr_{P+1}, xi_{P+1}}, P = 2*(lg&1).
  #pragma unroll
  for (int et = 0; et < 4; ++et) {
    f32x4 xe = xv[et];
    float qr[2], qi[2];
    #pragma unroll
    for (int dt = 0; dt < 2; ++dt) {
      f32x4 a = wacc[et][dt];
      float pr = xe[0] * a[0] - xe[1] * a[1] + xe[2] * a[2] - xe[3] * a[3];
      float pi = xe[0] * a[1] + xe[1] * a[0] + xe[2] * a[3] + xe[3] * a[2];
      // sum p-halves: lanes lg and lg^1 (lane xor 16) hold complementary p's
      qr[dt] = pr + __shfl_xor(pr, 16, 64);
      qi[dt] = pi + __shfl_xor(pi, 16, 64);
    }
    const int sel = lg & 1;                 // 0: store dt=0 pair, 1: dt=1 pair
    const int o = (lg >> 1) + 2 * sel;      // lane's assigned output o
    const float vr = sel ? qr[1] : qr[0];
    const float vi = sel ? qi[1] : qi[0];
    const int e = web + et * 16 + lrow;
    if (e < E) {
      f32x2 v2 = {vr, vi};
      *(f32x2*)(out + (size_t)e * 8 + o * 2) = v2;
    }
  }
}

extern "C" void kernel_launch(void* const* d_in, const int* in_sizes, int n_in,
                              void* d_out, int out_size, void* d_ws, size_t ws_size,
                              hipStream_t stream) {
  const float* x  = (const float*)d_in[0];
  const float* s  = (const float*)d_in[1];
  const float* W1 = (const float*)d_in[2];
  const float* b1 = (const float*)d_in[3];
  const float* W2 = (const float*)d_in[4];
  const float* b2 = (const float*)d_in[5];
  float* out = (float*)d_out;
  const int E = in_sizes[0] / 8;               // x is (E, 4, 2)
  const int blocks = (E + 255) / 256;          // 256 edges per block (4 waves)
  so2_fused_kernel<<<blocks, 256, 0, stream>>>(x, s, W1, b1, W2, b2, out, E);
}